// Round 7
// baseline (161.906 us; speedup 1.0000x reference)
//
#include <hip/hip_runtime.h>
#include <hip/hip_bf16.h>
#include <math.h>

// Problem constants
#define TT 32
#define NN 256
#define HID 64
#define OBS_LEN 128
#define SUB_LEN 18
#define IN_ROW 147      // OBS_LEN + SUB_LEN + 1
#define GJ 192          // 3*HID
#define GRU_IN 8384     // HID*(OBS_LEN+SUBDIM)
#define STATE 78
#define NSUB 6
#define NT_TILES 1572   // (8384/32) * (192/32) = 262*6

typedef __fp16 half2_t __attribute__((ext_vector_type(2)));

__device__ __forceinline__ float sigm(float x) {
    return 1.0f / (1.0f + __expf(-x));
}

__device__ __forceinline__ unsigned short f2bf(float f) {
    unsigned u = __float_as_uint(f);
    u += 0x7fffu + ((u >> 16) & 1u);     // round-to-nearest-even
    return (unsigned short)(u >> 16);
}

#if defined(__has_builtin)
#if __has_builtin(__builtin_amdgcn_fdot2)
#define HAVE_FDOT2 1
#endif
#endif

__device__ __forceinline__ float fdot2(half2_t a, half2_t b, float c) {
#ifdef HAVE_FDOT2
    return __builtin_amdgcn_fdot2(a, b, c, false);
#else
    return fmaf((float)a.x, (float)b.x, fmaf((float)a.y, (float)b.y, c));
#endif
}

// ================= K1: fused transpose + G + CB2 (block=256) =================
__global__ __launch_bounds__(256) void k_TGC(const float* __restrict__ w_ih,
                                             const float* __restrict__ obs_emb,
                                             const float* __restrict__ conv_w,
                                             const float* __restrict__ conv_b,
                                             const float* __restrict__ b_ih,
                                             float* __restrict__ wT,
                                             float* __restrict__ G,
                                             float* __restrict__ CB2) {
    int b = blockIdx.x;
    int tid = threadIdx.x;
    __shared__ float tile[32][33];
    __shared__ float red[4];

    if (b < NT_TILES) {
        int bx = b % 262, by = b / 262;
        int i0 = bx * 32, j0 = by * 32;
        int tx = tid & 31, ty = tid >> 5;   // 32 x 8
        #pragma unroll
        for (int a = 0; a < 4; a++)
            tile[ty + a * 8][tx] = w_ih[(size_t)(j0 + ty + a * 8) * GRU_IN + i0 + tx];
        __syncthreads();
        #pragma unroll
        for (int a = 0; a < 4; a++)
            wT[(size_t)(i0 + ty + a * 8) * GJ + j0 + tx] = tile[tx][ty + a * 8];
    } else if (b < NT_TILES + 16) {
        int i = (b - NT_TILES) * 256 + tid;
        int v = i & 15, d = (i >> 4) & 1, o = i >> 5;
        float acc = 0.f;
        const float* oe = obs_emb + v * 64;
        const float* cw = conv_w + o * 128 + d * 64;
        #pragma unroll
        for (int hd = 0; hd < 64; hd++) acc = fmaf(oe[hd], cw[hd], acc);
        G[i] = acc;
    } else {
        int j = b - (NT_TILES + 16);
        const float* wr = w_ih + (size_t)j * GRU_IN;
        float acc = 0.f;
        #pragma unroll 8
        for (int i = tid; i < 8192; i += 256) acc = fmaf(conv_b[i >> 6], wr[i], acc);
        for (int off = 32; off > 0; off >>= 1) acc += __shfl_down(acc, off, 64);
        if ((tid & 63) == 0) red[tid >> 6] = acc;
        __syncthreads();
        if (tid == 0) CB2[j] = b_ih[j] + red[0] + red[1] + red[2] + red[3];
    }
}

// ================= K2: fused E + Q (block=192, 512 blocks) =================
__global__ __launch_bounds__(192) void k_EQ(const float* __restrict__ inputs,
                                            const float* __restrict__ subtask_emb,
                                            const float* __restrict__ G,
                                            const float* __restrict__ wT,
                                            unsigned short* __restrict__ E16,
                                            float* __restrict__ Q) {
    int b = blockIdx.x;
    int j = threadIdx.x;

    if (b < 256) {
        int dp = b >> 1, half = b & 1;
        int d = dp >> 6, p = dp & 63;
        __shared__ __align__(16) float Gs[128 * 8];
        for (int e = j; e < 1024; e += GJ) {
            int o = e >> 3, vv = e & 7;
            Gs[e] = G[(o << 5) + (d << 4) + (half << 3) + vv];
        }
        __syncthreads();
        float acc[8];
        #pragma unroll
        for (int v = 0; v < 8; v++) acc[v] = 0.f;
        const float* wb = wT + (size_t)p * GJ + j;
        #pragma unroll 8
        for (int o = 0; o < 128; o++) {
            float w = wb[(size_t)(o * 64) * GJ];
            float4 g0 = *(const float4*)&Gs[o * 8];
            float4 g1 = *(const float4*)&Gs[o * 8 + 4];
            acc[0] = fmaf(g0.x, w, acc[0]);
            acc[1] = fmaf(g0.y, w, acc[1]);
            acc[2] = fmaf(g0.z, w, acc[2]);
            acc[3] = fmaf(g0.w, w, acc[3]);
            acc[4] = fmaf(g1.x, w, acc[4]);
            acc[5] = fmaf(g1.y, w, acc[5]);
            acc[6] = fmaf(g1.z, w, acc[6]);
            acc[7] = fmaf(g1.w, w, acc[7]);
        }
        unsigned short* Eo = E16 + ((size_t)(dp * 16 + half * 8)) * GJ;
        #pragma unroll
        for (int v = 0; v < 8; v++) Eo[v * GJ + j] = f2bf(acc[v]);
    } else {
        int n = b - 256;
        __shared__ int sidx[SUB_LEN];
        __shared__ __align__(16) float Ms[GJ * 8];   // [k][s], padded to 8
        if (j < SUB_LEN) sidx[j] = (int)inputs[(size_t)n * IN_ROW + OBS_LEN + j];
        __syncthreads();
        for (int e = j; e < NSUB * GJ; e += GJ) {
            int s = e / GJ, k = e - s * GJ;
            int row = sidx[s * 3 + (k >> 6)];
            Ms[k * 8 + s] = subtask_emb[row * 64 + (k & 63)];
        }
        __syncthreads();
        float acc[NSUB] = {0.f, 0.f, 0.f, 0.f, 0.f, 0.f};
        const float* base = wT + (size_t)8192 * GJ + j;
        #pragma unroll 8
        for (int k = 0; k < GJ; k++) {
            float w = base[(size_t)k * GJ];
            float4 m0 = *(const float4*)&Ms[k * 8];
            float2 m1 = *(const float2*)&Ms[k * 8 + 4];
            acc[0] = fmaf(m0.x, w, acc[0]);
            acc[1] = fmaf(m0.y, w, acc[1]);
            acc[2] = fmaf(m0.z, w, acc[2]);
            acc[3] = fmaf(m0.w, w, acc[3]);
            acc[4] = fmaf(m1.x, w, acc[4]);
            acc[5] = fmaf(m1.y, w, acc[5]);
        }
        for (int s = 0; s < NSUB; s++) Q[((size_t)n * NSUB + s) * GJ + j] = acc[s];
    }
}

// ===== K3: gx_all — 2 rows/block, dp split in halves, 16 loads in flight =====
__global__ __launch_bounds__(192, 4) void k_gx(const float* __restrict__ inputs,
                                               const unsigned short* __restrict__ E16,
                                               const float* __restrict__ CB2,
                                               float* __restrict__ gx_all) {
    int tn0 = blockIdx.x * 2;
    int tid = threadIdx.x;
    __shared__ __align__(16) int off[2][OBS_LEN];    // byte offsets (dp*16+id)*384
    __shared__ float part[2][48][5];                 // dp-half-1 partials (+1 pad)
    for (int e = tid; e < 2 * OBS_LEN; e += 192) {
        int row = e >> 7, dp = e & 127;
        int id = (int)inputs[(size_t)(tn0 + row) * IN_ROW + dp];
        off[row][dp] = (dp * 16 + id) * 384;
    }
    __syncthreads();
    int r = tid / 96;                 // row within block
    int rem = tid - r * 96;
    int dh = rem / 48;                // dp half
    int l = rem - dh * 48;
    int jj = l * 4;
    const char* base = (const char*)E16 + jj * 2;
    const int* id = off[r] + dh * 64;
    float a0 = 0.f, a1 = 0.f, a2 = 0.f, a3 = 0.f;
    #pragma unroll
    for (int dq = 0; dq < 4; dq++) {
        int4 o0 = *(const int4*)&id[dq * 16];
        int4 o1 = *(const int4*)&id[dq * 16 + 4];
        int4 o2 = *(const int4*)&id[dq * 16 + 8];
        int4 o3 = *(const int4*)&id[dq * 16 + 12];
        uint2 u0 = *(const uint2*)(base + o0.x);
        uint2 u1 = *(const uint2*)(base + o0.y);
        uint2 u2 = *(const uint2*)(base + o0.z);
        uint2 u3 = *(const uint2*)(base + o0.w);
        uint2 u4 = *(const uint2*)(base + o1.x);
        uint2 u5 = *(const uint2*)(base + o1.y);
        uint2 u6 = *(const uint2*)(base + o1.z);
        uint2 u7 = *(const uint2*)(base + o1.w);
        uint2 u8 = *(const uint2*)(base + o2.x);
        uint2 u9 = *(const uint2*)(base + o2.y);
        uint2 uA = *(const uint2*)(base + o2.z);
        uint2 uB = *(const uint2*)(base + o2.w);
        uint2 uC = *(const uint2*)(base + o3.x);
        uint2 uD = *(const uint2*)(base + o3.y);
        uint2 uE = *(const uint2*)(base + o3.z);
        uint2 uF = *(const uint2*)(base + o3.w);
        #define ACC(u) do { \
            a0 += __uint_as_float((u).x << 16); \
            a1 += __uint_as_float((u).x & 0xffff0000u); \
            a2 += __uint_as_float((u).y << 16); \
            a3 += __uint_as_float((u).y & 0xffff0000u); } while (0)
        ACC(u0); ACC(u1); ACC(u2); ACC(u3);
        ACC(u4); ACC(u5); ACC(u6); ACC(u7);
        ACC(u8); ACC(u9); ACC(uA); ACC(uB);
        ACC(uC); ACC(uD); ACC(uE); ACC(uF);
        #undef ACC
    }
    if (dh == 1) {
        part[r][l][0] = a0; part[r][l][1] = a1;
        part[r][l][2] = a2; part[r][l][3] = a3;
    }
    __syncthreads();
    if (dh == 0) {
        float4 cb = *(const float4*)(CB2 + jj);
        float4 o4;
        o4.x = a0 + part[r][l][0] + cb.x;
        o4.y = a1 + part[r][l][1] + cb.y;
        o4.z = a2 + part[r][l][2] + cb.z;
        o4.w = a3 + part[r][l][3] + cb.w;
        *(float4*)(gx_all + (size_t)(tn0 + r) * GJ + jj) = o4;
    }
}

// ================= K4: recurrence — 1 wave/n, f16 dot2, critic post-pass =====
__global__ __launch_bounds__(64, 1) void k_rec(const float* __restrict__ inputs,
                                               const float* __restrict__ hx,
                                               const float* __restrict__ w_hh,
                                               const float* __restrict__ b_hh,
                                               const float* __restrict__ critic_w,
                                               const float* __restrict__ critic_b,
                                               const float* __restrict__ phi_w,
                                               const float* __restrict__ phi_b,
                                               const float* __restrict__ Q,
                                               const float* __restrict__ gx_all,
                                               float* __restrict__ out) {
    int n = blockIdx.x;
    int lane = threadIdx.x;   // 0..63, lane == h-index

    __shared__ __align__(16) float gx_lds[TT * GJ];   // 24 KB
    __shared__ __align__(16) __fp16 h16[64];          // h exchanged as f16
    __shared__ float h_all[TT][65];                   // hn per step (+1 pad)
    __shared__ float cw_sh[64];
    __shared__ float act_sh[TT];

    // preload gx slice (coalesced float4)
    for (int e = lane * 4; e < TT * GJ; e += 64 * 4) {
        int t = e / GJ, j = e - t * GJ;
        *(float4*)&gx_lds[e] = *(const float4*)(gx_all + ((size_t)t * NN + n) * GJ + j);
    }
    if (lane < TT)
        act_sh[lane] = inputs[((size_t)lane * NN + n) * IN_ROW + (IN_ROW - 1)];

    // f16 weights: 3 gate rows for this lane (96 half2 regs)
    half2_t wv0[32], wv1[32], wv2[32];
    {
        const float4* r0 = (const float4*)(w_hh + (size_t)lane * 64);
        const float4* r1 = (const float4*)(w_hh + (size_t)(64 + lane) * 64);
        const float4* r2 = (const float4*)(w_hh + (size_t)(128 + lane) * 64);
        #pragma unroll
        for (int h4 = 0; h4 < 16; h4++) {
            float4 a = r0[h4];
            wv0[2*h4]   = __builtin_amdgcn_cvt_pkrtz(a.x, a.y);
            wv0[2*h4+1] = __builtin_amdgcn_cvt_pkrtz(a.z, a.w);
            float4 c = r1[h4];
            wv1[2*h4]   = __builtin_amdgcn_cvt_pkrtz(c.x, c.y);
            wv1[2*h4+1] = __builtin_amdgcn_cvt_pkrtz(c.z, c.w);
            float4 d = r2[h4];
            wv2[2*h4]   = __builtin_amdgcn_cvt_pkrtz(d.x, d.y);
            wv2[2*h4+1] = __builtin_amdgcn_cvt_pkrtz(d.z, d.w);
        }
    }
    // φ replicated per-lane as f16 pairs (32 regs)
    half2_t ph[32];
    {
        const float4* pp = (const float4*)phi_w;
        #pragma unroll
        for (int h4 = 0; h4 < 16; h4++) {
            float4 a = pp[h4];
            ph[2*h4]   = __builtin_amdgcn_cvt_pkrtz(a.x, a.y);
            ph[2*h4+1] = __builtin_amdgcn_cvt_pkrtz(a.z, a.w);
        }
    }
    float q0[NSUB], q1[NSUB], q2[NSUB];
    #pragma unroll
    for (int s = 0; s < NSUB; s++) {
        const float* qb = Q + ((size_t)n * NSUB + s) * GJ;
        q0[s] = qb[lane]; q1[s] = qb[64 + lane]; q2[s] = qb[128 + lane];
    }
    float bh0 = b_hh[lane], bh1 = b_hh[64 + lane], bh2 = b_hh[128 + lane];
    cw_sh[lane] = critic_w[lane];
    float phib = phi_b[0], crtb = critic_b[0];

    // init h, p, new_episode (wave-local)
    float v0 = hx[(size_t)n * STATE + lane];
    float v1 = (lane < STATE - 64) ? hx[(size_t)n * STATE + 64 + lane] : 0.f;
    unsigned long long bal0 = __ballot(v0 != 0.f);
    unsigned long long bal1 = __ballot((lane < STATE - 64) && v1 != 0.f);
    bool ne = ((bal0 | bal1) == 0ULL);
    float h_own = hx[(size_t)n * STATE + 2 + lane];
    float p0, p1, p2, p3, p4, p5;
    {
        const float* pb = hx + (size_t)n * STATE + 72;
        p0 = pb[0]; p1 = pb[1]; p2 = pb[2]; p3 = pb[3]; p4 = pb[4]; p5 = pb[5];
    }
    if (ne) p0 = 1.0f;
    h16[lane] = (__fp16)h_own;

    // finalize step tf: needs pc (φ·h_tf), updates p, writes probs/p outputs
    auto finalize = [&](int tf, float pc) {
        float c = sigm(pc + phib);
        float n0 = fmaf(c, (p0 * p5)      - p0, p0);
        float n1 = fmaf(c, (p0 + p1 * p5) - p1, p1);
        float n2 = fmaf(c, (p1 + p2 * p5) - p2, p2);
        float n3 = fmaf(c, (p2 + p3 * p5) - p3, p3);
        float n4 = fmaf(c, (p3 + p4 * p5) - p4, p4);
        float n5 = fmaf(c, (p4 + p5 * p5) - p5, p5);
        float psum = ((n0 + n1) + (n2 + n3)) + (n4 + n5);
        float rinv = 1.0f / psum;
        if (lane < 12) {
            int s = (lane < 6) ? lane : lane - 6;
            float pp = n0;
            pp = (s == 1) ? n1 : pp;
            pp = (s == 2) ? n2 : pp;
            pp = (s == 3) ? n3 : pp;
            pp = (s == 4) ? n4 : pp;
            pp = (s == 5) ? n5 : pp;
            size_t fb = ((size_t)tf * NN + n) * STATE;
            out[fb + ((lane < 6) ? (72 + lane) : (66 + lane - 6))] =
                (lane < 6) ? pp : pp * rinv;
        }
        p0 = n0; p1 = n1; p2 = n2; p3 = n3; p4 = n4; p5 = n5;
    };

    for (int t = 0; t < TT; t++) {
        // ---- read h (= hn_{t-1}) from LDS as f16 pairs ----
        uint4 raw[8];
        #pragma unroll
        for (int rix = 0; rix < 8; rix++) raw[rix] = ((const uint4*)h16)[rix];
        half2_t h2[32];
        {
            const unsigned* rw = (const unsigned*)raw;
            #pragma unroll
            for (int k = 0; k < 32; k++) h2[k] = __builtin_bit_cast(half2_t, rw[k]);
        }

        // ---- dots: 3 gates + φ, 4 chains of 8 each (16-way ILP) ----
        float A0 = 0.f, B0 = 0.f, C0 = 0.f, D0 = 0.f;
        float A1 = 0.f, B1 = 0.f, C1 = 0.f, D1 = 0.f;
        float A2 = 0.f, B2 = 0.f, C2 = 0.f, D2 = 0.f;
        float PA = 0.f, PB = 0.f, PC = 0.f, PD = 0.f;
        #pragma unroll
        for (int k = 0; k < 8; k++) {
            A0 = fdot2(h2[k], wv0[k], A0);
            B0 = fdot2(h2[8 + k], wv0[8 + k], B0);
            C0 = fdot2(h2[16 + k], wv0[16 + k], C0);
            D0 = fdot2(h2[24 + k], wv0[24 + k], D0);
            A1 = fdot2(h2[k], wv1[k], A1);
            B1 = fdot2(h2[8 + k], wv1[8 + k], B1);
            C1 = fdot2(h2[16 + k], wv1[16 + k], C1);
            D1 = fdot2(h2[24 + k], wv1[24 + k], D1);
            A2 = fdot2(h2[k], wv2[k], A2);
            B2 = fdot2(h2[8 + k], wv2[8 + k], B2);
            C2 = fdot2(h2[16 + k], wv2[16 + k], C2);
            D2 = fdot2(h2[24 + k], wv2[24 + k], D2);
            PA = fdot2(h2[k], ph[k], PA);
            PB = fdot2(h2[8 + k], ph[8 + k], PB);
            PC = fdot2(h2[16 + k], ph[16 + k], PC);
            PD = fdot2(h2[24 + k], ph[24 + k], PD);
        }
        float pc = (PA + PB) + (PC + PD);

        // ---- finalize previous step's c/p/probs (uses pc = φ·hn_{t-1}) ----
        if (t > 0) finalize(t - 1, pc);

        // ---- gx with p_{t-1} ----
        float gx0 = gx_lds[t * GJ + lane];
        float gx1 = gx_lds[t * GJ + 64 + lane];
        float gx2 = gx_lds[t * GJ + 128 + lane];
        gx0 = fmaf(p0, q0[0], gx0); gx1 = fmaf(p0, q1[0], gx1); gx2 = fmaf(p0, q2[0], gx2);
        gx0 = fmaf(p1, q0[1], gx0); gx1 = fmaf(p1, q1[1], gx1); gx2 = fmaf(p1, q2[1], gx2);
        gx0 = fmaf(p2, q0[2], gx0); gx1 = fmaf(p2, q1[2], gx1); gx2 = fmaf(p2, q2[2], gx2);
        gx0 = fmaf(p3, q0[3], gx0); gx1 = fmaf(p3, q1[3], gx1); gx2 = fmaf(p3, q2[3], gx2);
        gx0 = fmaf(p4, q0[4], gx0); gx1 = fmaf(p4, q1[4], gx1); gx2 = fmaf(p4, q2[4], gx2);
        gx0 = fmaf(p5, q0[5], gx0); gx1 = fmaf(p5, q1[5], gx1); gx2 = fmaf(p5, q2[5], gx2);

        float gh0 = bh0 + (A0 + B0) + (C0 + D0);
        float gh1 = bh1 + (A1 + B1) + (C1 + D1);
        float gh2 = bh2 + (A2 + B2) + (C2 + D2);

        float r = sigm(gx0 + gh0);
        float z = sigm(gx1 + gh1);
        float x2 = fmaf(r, gh2, gx2);
        float e2 = __expf(2.f * x2);
        float nv = 1.f - 2.f / (e2 + 1.f);           // tanh, overflow-safe
        float hn = fmaf(z, h_own - nv, nv);          // (1-z)*n + z*h

        // ---- outputs for step t: h + act (critic handled post-loop) ----
        size_t base = ((size_t)t * NN + n) * STATE;
        out[base + 2 + lane] = hn;
        if (lane == 1) out[base + 0] = act_sh[t];

        // ---- state handoff ----
        h16[lane] = (__fp16)hn;
        h_all[t][lane] = hn;
        h_own = hn;
    }

    // ---- epilogue: finalize step 31 ----
    {
        uint4 raw[8];
        #pragma unroll
        for (int rix = 0; rix < 8; rix++) raw[rix] = ((const uint4*)h16)[rix];
        const unsigned* rw = (const unsigned*)raw;
        float PA = 0.f, PB = 0.f;
        #pragma unroll
        for (int k = 0; k < 16; k++) {
            PA = fdot2(__builtin_bit_cast(half2_t, rw[k]), ph[k], PA);
            PB = fdot2(__builtin_bit_cast(half2_t, rw[16 + k]), ph[16 + k], PB);
        }
        finalize(TT - 1, PA + PB);
    }

    // ---- post-pass: critic values for all 32 steps in parallel ----
    float vlast;
    {
        int tp = lane >> 1, half = lane & 1;
        const float* hr = &h_all[tp][half * 32];
        const float* cr = &cw_sh[half * 32];
        float vc = 0.f;
        #pragma unroll
        for (int k = 0; k < 32; k++) vc = fmaf(hr[k], cr[k], vc);
        vc += __shfl_xor(vc, 1, 64);
        float vt = vc + crtb;
        if (half == 0) out[((size_t)tp * NN + n) * STATE + 1] = vt;
        vlast = __shfl(vt, 62, 64);
    }

    // ---- final-state duplicate block (p0..p5 hold p_{31}) ----
    {
        float psum = ((p0 + p1) + (p2 + p3)) + (p4 + p5);
        float rinv = 1.0f / psum;
        size_t fs = (size_t)TT * NN * STATE + (size_t)n * STATE;
        out[fs + 2 + lane] = h_own;
        if (lane < 12) {
            int s = (lane < 6) ? lane : lane - 6;
            float pp = p0;
            pp = (s == 1) ? p1 : pp;
            pp = (s == 2) ? p2 : pp;
            pp = (s == 3) ? p3 : pp;
            pp = (s == 4) ? p4 : pp;
            pp = (s == 5) ? p5 : pp;
            out[fs + ((lane < 6) ? (72 + lane) : (66 + lane - 6))] =
                (lane < 6) ? pp : pp * rinv;
        } else if (lane == 12) {
            out[fs + 0] = act_sh[TT - 1];
        } else if (lane == 13) {
            out[fs + 1] = vlast;
        }
    }
}

extern "C" void kernel_launch(void* const* d_in, const int* in_sizes, int n_in,
                              void* d_out, int out_size, void* d_ws, size_t ws_size,
                              hipStream_t stream) {
    const float* inputs      = (const float*)d_in[0];
    const float* hx          = (const float*)d_in[1];
    const float* subtask_emb = (const float*)d_in[2];
    const float* obs_emb     = (const float*)d_in[3];
    const float* conv_w      = (const float*)d_in[4];
    const float* conv_b      = (const float*)d_in[5];
    const float* w_ih        = (const float*)d_in[6];
    const float* w_hh        = (const float*)d_in[7];
    const float* b_ih        = (const float*)d_in[8];
    const float* b_hh        = (const float*)d_in[9];
    const float* critic_w    = (const float*)d_in[10];
    const float* critic_b    = (const float*)d_in[11];
    const float* phi_w       = (const float*)d_in[12];
    const float* phi_b       = (const float*)d_in[13];
    float* out = (float*)d_out;

    // workspace layout (floats)
    float* ws   = (float*)d_ws;
    float* wT   = ws;                                   // 8384*192 f
    float* G    = wT + (size_t)GRU_IN * GJ;             // 4096 f
    float* CB2  = G + 4096;                             // 192 f
    float* Ef   = CB2 + 192;                            // E16: 393,216 ushort
    unsigned short* E16 = (unsigned short*)Ef;
    float* Q    = Ef + 196608;                          // 256*6*192 f
    float* gx   = Q + (size_t)NN * NSUB * GJ;           // 32*256*192 f

    k_TGC<<<NT_TILES + 16 + GJ, 256, 0, stream>>>(w_ih, obs_emb, conv_w, conv_b,
                                                  b_ih, wT, G, CB2);
    k_EQ<<<512, GJ, 0, stream>>>(inputs, subtask_emb, G, wT, E16, Q);
    k_gx<<<TT * NN / 2, GJ, 0, stream>>>(inputs, E16, CB2, gx);
    k_rec<<<NN, 64, 0, stream>>>(inputs, hx, w_hh, b_hh, critic_w, critic_b,
                                 phi_w, phi_b, Q, gx, out);
}